// Round 10
// baseline (240.076 us; speedup 1.0000x reference)
//
#include <hip/hip_runtime.h>
#include <stdint.h>

typedef unsigned short u16;
typedef unsigned int u32;
typedef __bf16 bf16x8 __attribute__((ext_vector_type(8)));
typedef float f32x4 __attribute__((ext_vector_type(4)));

#define BM 128
#define BN 128
#define BK 64

__device__ __forceinline__ u16 f2bf(float x) {
  union { float f; uint32_t u; } c; c.f = x;
  uint32_t r = (c.u + 0x7FFFu + ((c.u >> 16) & 1u)) >> 16;
  return (u16)r;
}
__device__ __forceinline__ float bf2f(u16 v) {
  union { uint32_t u; float f; } c; c.u = ((uint32_t)v) << 16;
  return c.f;
}

// async global->LDS, 16B per lane; LDS dest = wave-uniform base + lane*16
__device__ __forceinline__ void async_copy16(const u16* g, u16* l) {
  __builtin_amdgcn_global_load_lds(
      (const __attribute__((address_space(1))) void*)g,
      (__attribute__((address_space(3))) void*)l,
      16, 0, 0);
}

__global__ void zerofill_u16(u16* __restrict__ p) {
  long i = (long)blockIdx.x * 256 + threadIdx.x;
  p[i] = 0;
}

// ---------- PV split-K combine: out[rows 1024..2047] = (P0+P1)/sigma -------
// P aliases the dead QK buffer (scores completed before PV in stream order).
// Deterministic two-term add; dtype-adaptive writeout.
__global__ __launch_bounds__(256)
void pv_combine(const float* __restrict__ P, const float* __restrict__ sigma,
                void* __restrict__ out, const u32* __restrict__ flag)
{
  const long e = ((long)blockIdx.x * 256 + threadIdx.x) * 4;  // 4 cols/thread
  const int bz = (int)(e >> 20);
  const int r  = (int)((e >> 10) & 1023);
  const int c  = (int)(e & 1023);
  const f32x4 a = *(const f32x4*)(P + e);
  const f32x4 b = *(const f32x4*)(P + 4194304 + e);
  const float inv = 1.0f / sigma[bz * 2048 + 1024 + r];
  const long ob = (long)bz * 2097152 + (long)(1024 + r) * 1024 + c;
  if (*flag > 32) {
    f32x4 o;
#pragma unroll
    for (int j = 0; j < 4; ++j) o[j] = (a[j] + b[j]) * inv;
    *(f32x4*)((float*)out + ob) = o;
  } else {
    u16 o[4];
#pragma unroll
    for (int j = 0; j < 4; ++j) o[j] = f2bf((a[j] + b[j]) * inv);
    *(uint2*)((u16*)out + ob) = *(uint2*)o;
  }
}

// ---------- fused prep: dtype self-detect + x normalize + W transnorm + ----
// sigma zero. Every block samples the SAME first 8192 u16 of Wq: bf16
// weights give 0 exp==0xFF hits; f32 mantissa halves give ~16 (P(0)~1e-7).
__global__ __launch_bounds__(256)
void prep(const void* __restrict__ xs, const void* __restrict__ w0,
          const void* __restrict__ w1, const void* __restrict__ w2,
          u16* __restrict__ xn, u16* __restrict__ WT3, u32* __restrict__ flag,
          float* __restrict__ sigma, int nxb)
{
  __shared__ int sh_hits;
  __shared__ u16 tile[64][72];
  if (threadIdx.x == 0) sh_hits = 0;
  __syncthreads();
  {
    const u16* w = (const u16*)w0;
    int h = 0;
    for (int i = threadIdx.x; i < 8192; i += 256)
      if ((w[i] & 0x7F80u) == 0x7F80u) h++;
    if (h) atomicAdd(&sh_hits, h);
  }
  __syncthreads();
  const bool isf32 = (sh_hits > 0);
  const int blk = blockIdx.x;
  const int tid = threadIdx.x;
  if (blk == 0 && tid == 0) *flag = isf32 ? 1000u : 0u;

  if (blk < nxb) {
    long i = ((long)blk * 256 + tid) * 8;
    u16 o[8];
    if (isf32) {
      const float* s = (const float*)xs + i;
      f32x4 a = *(const f32x4*)s;
      f32x4 b = *(const f32x4*)(s + 4);
#pragma unroll
      for (int c = 0; c < 4; ++c) { o[c] = f2bf(a[c]); o[c + 4] = f2bf(b[c]); }
    } else {
      *(uint4*)o = *(const uint4*)((const u16*)xs + i);
    }
    *(uint4*)(xn + i) = *(uint4*)o;
  } else if (blk < nxb + 768) {
    const int Dd = 1024;
    int t = blk - nxb;
    int z = t >> 8;
    int r = t & 255;
    const int r0 = (r >> 4) * 64, c0 = (r & 15) * 64;
    const void* src = (z == 0) ? w0 : (z == 1) ? w1 : w2;
    u16* out = WT3 + (long)z * Dd * Dd;
#pragma unroll
    for (int p = 0; p < 2; ++p) {
      int v = tid + p * 256;
      int row = v >> 3, c8 = (v & 7) * 8;
      u16 tt[8];
      if (isf32) {
        const float* sp = (const float*)src + (long)(r0 + row) * Dd + c0 + c8;
        f32x4 a = *(const f32x4*)sp;
        f32x4 b = *(const f32x4*)(sp + 4);
#pragma unroll
        for (int c = 0; c < 4; ++c) { tt[c] = f2bf(a[c]); tt[c + 4] = f2bf(b[c]); }
      } else {
        *(uint4*)tt = *(const uint4*)((const u16*)src + (long)(r0 + row) * Dd + c0 + c8);
      }
#pragma unroll
      for (int c = 0; c < 8; ++c) tile[row][c8 + c] = tt[c];
    }
    __syncthreads();
#pragma unroll
    for (int p = 0; p < 2; ++p) {
      int v = tid + p * 256;
      int oc = v >> 3, r8 = (v & 7) * 8;
      union { uint4 q; u16 s[8]; } tt;
#pragma unroll
      for (int c = 0; c < 8; ++c) tt.s[c] = tile[r8 + c][oc];
      *(uint4*)(out + (long)(c0 + oc) * Dd + r0 + r8) = tt.q;
    }
  } else {
    int t = blk - (nxb + 768);
    *(f32x4*)(sigma + ((long)t * 256 + tid) * 4) = f32x4{0.f, 0.f, 0.f, 0.f};
  }
}

// ---------- NT GEMM, 16x16x32 MFMA core (r5/r7-verified: 0 conflicts) ------
// LDS XOR-swizzled on the global-read side: slot [r][p] holds global chunk
// p^(r&7). 16-row fragment geometry => only 2-way bank aliasing (free).
// DO NOT switch to 32x32 fragments: 4-way structural conflict (r6).
// DO NOT replace with 1-blk/CU pipelined variants: r1/r2/r3 all regressed.
// DO NOT shrink BM to 64 to add blocks: r7 regressed PV 44->52 us — staging
// bytes per MFMA rise 50%; occupancy gain did not pay for it.
// r9: QK|VT fusion (MODE 5) = -10 us. Fused dispatch runs at ~851 TF, the
// m97-structure ceiling — do not re-attack.
// __launch_bounds__(256,4): 32KB LDS x4 = 128KB <= 160KB; 64 arch + 64 acc
// VGPR = 128 unified -> 4 waves/SIMD.
// MODE 2: PV monolithic (Tier C only) — bf16/f32 out, /sigma[row].
// MODE 3: scores — supertile-ordered triangular grid (136 tiles/batch).
//         bf16 exp(acc*scale), causal mask on diagonal, atomic row-sums.
// MODE 5: fused QK|VT: t<ntri QK tile; t>=ntri VT tile (operands swapped,
//         col->batch write). sigStride carries VT bn count.
// MODE 6: PV split-K (r10): grid (8, 24, z). vb<8: bm=vb, full causal range
//         [0, 2(bm+1)) tiles, direct /sigma writeout (bitwise == MODE 2).
//         vb>=8: bm=8+((vb-8)>>1), half h=(vb-8)&1 covers [h*L,(h+1)*L),
//         L=bm+1<=16; raw f32 partial to P (=vtOut alias of dead QK buf) at
//         [h][bz][row-1024][col]. Halves the long-block critical path
//         (r9 PMC: PV was crit-path-bound on nk=32 blocks, Occ 11%).
template <int MODE>
__global__ __launch_bounds__(256, 4)
void gemm_nt(const u16* __restrict__ A, const u16* __restrict__ B, void* __restrict__ Cv,
             const u32* __restrict__ flag, float* __restrict__ sigma, int sigStride,
             int K, int lda, int ldb, int ldc,
             long sA, long sB, long sC, long cOff,
             float scale, int trik, int ntri, u16* __restrict__ vtOut)
{
  __shared__ u16 As[BM * BK];
  __shared__ u16 Bs[BN * BK];
  const int bz = blockIdx.z;
  const int tid = threadIdx.x;

  int bm, bn;
  bool isVT = false;
  int part = -1;
  if constexpr (MODE == 3) {
    // supertile-ordered triangle decode (16x16 tiles, 4x4 supertiles)
    const int t = blockIdx.x;
    const int cum[11] = {0, 10, 26, 36, 52, 68, 78, 94, 110, 126, 136};
    const int ssm[10] = {0, 1, 1, 2, 2, 2, 3, 3, 3, 3};
    const int ssn[10] = {0, 0, 1, 0, 1, 2, 0, 1, 2, 3};
    int s = 0;
    while (cum[s + 1] <= t) ++s;
    const int l = t - cum[s];
    const int sm = ssm[s], sn = ssn[s];
    int tm, tn;
    if (sm == sn) {                 // diagonal supertile: triangular 10
      tm = 0;
      while ((tm + 1) * (tm + 2) / 2 <= l) ++tm;
      tn = l - tm * (tm + 1) / 2;
    } else { tm = l >> 2; tn = l & 3; }
    bm = sm * 4 + tm;
    bn = sn * 4 + tn;
    (void)ntri;
  } else if constexpr (MODE == 5) {
    const int t = blockIdx.x;
    if (t < ntri) {                 // QK half: bn fastest (16 wide)
      bm = t >> 4; bn = t & 15;
    } else {                        // VT half: bn fastest (sigStride wide)
      isVT = true;
      const int t2 = t - ntri;
      bm = t2 / sigStride; bn = t2 % sigStride;
      const u16* tmp = A;
      A = B + (long)2048 * 1024;    // WvT base inside WT3
      B = tmp;                      // xn becomes the B operand
    }
  } else if constexpr (MODE == 6) {
    bn = blockIdx.x;
    const int vb = blockIdx.y;
    if (vb < 8) { bm = vb; }
    else { bm = 8 + ((vb - 8) >> 1); part = (vb - 8) & 1; }
  } else {
    bm = blockIdx.y;
    if (trik) bm = gridDim.y - 1 - bm;         // longest blocks first
    bn = blockIdx.x;
  }

  A += (long)bz * sA;
  B += (long)bz * sB;

  const int wid  = tid >> 6;
  const int lane = tid & 63;
  const int l16  = lane & 15;
  const int lk   = lane >> 4;                   // 0..3
  const int srow = lane >> 3;                   // 0..7 (staging row in slab)
  const int swz  = ((lane & 7) ^ srow) * 8;     // swizzled staging col
  const int m0 = bm * BM, n0 = bn * BN;

  int nk = K / BK;
  if (trik) { int lim = (m0 + BM) / BK; if (lim < nk) nk = lim; }
  int kts = 0;
  if constexpr (MODE == 6) {
    const int L = bm + 1;
    if (part < 0) { kts = 0;        nk = 2 * L; }
    else          { kts = part * L; nk = kts + L; }
  }

  f32x4 acc[4][4] = {};

  for (int kt = kts; kt < nk; ++kt) {
    const int k0 = kt * BK;
#pragma unroll
    for (int c = 0; c < 4; ++c) {
      const int rb = wid * 32 + c * 8;          // wave-uniform 8-row slab base
      async_copy16(A + (long)(m0 + rb + srow) * lda + (k0 + swz), As + rb * BK);
      async_copy16(B + (long)(n0 + rb + srow) * ldb + (k0 + swz), Bs + rb * BK);
    }
    __syncthreads();
#pragma unroll
    for (int kh = 0; kh < 2; ++kh) {
      bf16x8 av[4], bv[4];
#pragma unroll
      for (int i = 0; i < 4; ++i) {
        const int Ra = (wid >> 1) * 64 + i * 16 + l16;
        const int Rb = (wid & 1)  * 64 + i * 16 + l16;
        const int ca = ((kh * 4 + lk) ^ (l16 & 7)) * 8;  // de-swizzled chunk
        av[i] = *(const bf16x8*)(As + Ra * BK + ca);
        bv[i] = *(const bf16x8*)(Bs + Rb * BK + ca);
      }
#pragma unroll
      for (int mi = 0; mi < 4; ++mi)
#pragma unroll
        for (int ni = 0; ni < 4; ++ni)
          acc[mi][ni] = __builtin_amdgcn_mfma_f32_16x16x32_bf16(av[mi], bv[ni], acc[mi][ni], 0, 0, 0);
    }
    __syncthreads();
  }

  // C/D layout (m89-verified): col = lane&15, row = (lane>>4)*4 + reg
  const int rb0 = m0 + (wid >> 1) * 64;
  const int cb0 = n0 + (wid & 1) * 64;
  const long cbase = (long)bz * sC + cOff;

  if constexpr (MODE == 3) {
    // exp + causal mask + bf16 store + atomic row-sums (of the SAME
    // bf16-rounded values PV will consume, so weight errors cancel)
    u16* Cp = (u16*)Cv;
    const bool diag = (bm == bn);
    float* sig = sigma + (long)bz * sigStride;
#pragma unroll
    for (int mi = 0; mi < 4; ++mi)
#pragma unroll
      for (int r = 0; r < 4; ++r) {
        const int row = rb0 + mi * 16 + lk * 4 + r;
        float part2 = 0.f;
#pragma unroll
        for (int ni = 0; ni < 4; ++ni) {
          const int col = cb0 + ni * 16 + l16;
          float ev = __expf(acc[mi][ni][r] * scale);
          if (diag && col > row) ev = 0.f;
          u16 b = f2bf(ev);
          part2 += bf2f(b);
          Cp[cbase + (long)row * ldc + col] = b;
        }
#pragma unroll
        for (int o = 1; o < 16; o <<= 1) part2 += __shfl_xor(part2, o);
        if (l16 == 0) atomicAdd(&sig[row], part2);
      }
  } else if constexpr (MODE == 5) {
    if (isVT) {
      // VT writeout: row=d, col=global s; batch from col>>11
#pragma unroll
      for (int mi = 0; mi < 4; ++mi)
#pragma unroll
        for (int r = 0; r < 4; ++r) {
          const int row = rb0 + mi * 16 + lk * 4 + r;
#pragma unroll
          for (int ni = 0; ni < 4; ++ni) {
            const int col = cb0 + ni * 16 + l16;
            const long idx = (long)row * ldc + (long)(col >> 11) * sC + (col & 2047);
            vtOut[idx] = f2bf(acc[mi][ni][r]);
          }
        }
    } else {
      // QK writeout (bf16, row-major ldc=2048)
      u16* Cp = (u16*)Cv;
#pragma unroll
      for (int mi = 0; mi < 4; ++mi)
#pragma unroll
        for (int r = 0; r < 4; ++r) {
          const int row = rb0 + mi * 16 + lk * 4 + r;
#pragma unroll
          for (int ni = 0; ni < 4; ++ni) {
            const int col = cb0 + ni * 16 + l16;
            Cp[(long)row * 2048 + col] = f2bf(acc[mi][ni][r]);
          }
        }
    }
  } else if constexpr (MODE == 6) {
    if (part < 0) {
      // rows < 1024: direct /sigma writeout (identical to MODE 2)
      const bool f32out = (*flag > 32);
      const float* sig = sigma + (long)bz * sigStride;
#pragma unroll
      for (int mi = 0; mi < 4; ++mi)
#pragma unroll
        for (int r = 0; r < 4; ++r) {
          const int row = rb0 + mi * 16 + lk * 4 + r;
          const float rs = 1.0f / sig[row];
#pragma unroll
          for (int ni = 0; ni < 4; ++ni) {
            const int col = cb0 + ni * 16 + l16;
            const float v = acc[mi][ni][r] * rs;
            const long idx = cbase + (long)row * ldc + col;
            if (f32out) ((float*)Cv)[idx] = v;
            else        ((u16*)Cv)[idx]   = f2bf(v);
          }
        }
    } else {
      // rows >= 1024: raw f32 partial -> P[part][bz][row-1024][col]
      float* pb = (float*)vtOut;
      const long pbase = (long)part * 4194304 + (long)bz * 1048576;
#pragma unroll
      for (int mi = 0; mi < 4; ++mi)
#pragma unroll
        for (int r = 0; r < 4; ++r) {
          const int row = rb0 + mi * 16 + lk * 4 + r;
#pragma unroll
          for (int ni = 0; ni < 4; ++ni) {
            const int col = cb0 + ni * 16 + l16;
            pb[pbase + (long)(row - 1024) * 1024 + col] = acc[mi][ni][r];
          }
        }
    }
  } else {
    const bool f32out = (MODE == 2) && (*flag > 32);
    const float* sig = (MODE == 2) ? (sigma + (long)bz * sigStride) : nullptr;
#pragma unroll
    for (int mi = 0; mi < 4; ++mi)
#pragma unroll
      for (int r = 0; r < 4; ++r) {
        const int row = rb0 + mi * 16 + lk * 4 + r;
        float rs = scale;
        if constexpr (MODE == 2) rs = 1.0f / sig[row];
#pragma unroll
        for (int ni = 0; ni < 4; ++ni) {
          const int col = cb0 + ni * 16 + l16;
          const float v = acc[mi][ni][r] * rs;
          const long idx = cbase + (long)row * ldc + col;
          if (f32out) ((float*)Cv)[idx] = v;
          else        ((u16*)Cv)[idx]   = f2bf(v);
        }
      }
  }
}

extern "C" void kernel_launch(void* const* d_in, const int* in_sizes, int n_in,
                              void* d_out, int out_size, void* d_ws, size_t ws_size,
                              hipStream_t stream)
{
  (void)in_sizes; (void)n_in; (void)out_size;
  const int Bb = 4, S = 2048, D = 1024, D2 = 2048;
  const long SD  = (long)S * D;           // 2,097,152
  const long SD2 = (long)S * D2;          // 4,194,304 (QK per-batch stride)
  const long SS  = (long)S * S;           // 4,194,304
  const long N_X = (long)Bb * SD;         // 8,388,608
  const long N_W = (long)D * D;           // 1,048,576
  const int NTRI = 16 * 17 / 2;           // 136 lower-triangle tiles

  char* ws = (char*)d_ws;
  size_t off = 0;
  auto take = [&](size_t bytes) -> void* {
    void* p = ws + off;
    off = (off + bytes + 255) & ~((size_t)255);
    return p;
  };

  // ---- common allocations (~22 MB)
  u32*   flag  = (u32*)take(4096);
  float* sigma = (float*)take((size_t)Bb * S * 4);  // 32 KB row-sums
  u16*   xn    = (u16*)take((size_t)N_X * 2);
  u16*   WT3   = (u16*)take((size_t)3 * N_W * 2);
  const size_t off_common = off;

  const size_t needA = off_common + (size_t)(Bb * SD2 * 2)     // QK 32 MB
                     + (size_t)(N_X * 2)                       // VT 16 MB
                     + (size_t)(Bb * SS * 2) + 4096;           // E bf16 32 MB
  const size_t needC = off_common + (size_t)(SD2 * 2)          // QKb 8 MB
                     + (size_t)(SD * 2)                        // VTb 4 MB
                     + (size_t)(SS * 2) + 4096;                // Eb 8 MB

  if (ws_size < needC) {
    zerofill_u16<<<(int)(N_X / 256), 256, 0, stream>>>((u16*)d_out);
    return;
  }

  // ---- fused prep: detect + normalize x + transnorm W + zero sigma ----
  const int nxb = (int)(N_X / 2048);   // 4096 x-blocks
  prep<<<nxb + 768 + 8, 256, 0, stream>>>(d_in[0], d_in[1], d_in[2], d_in[3],
                                          xn, WT3, flag, sigma, nxb);

  const float scl = 0.03125f;  // 1024^-0.5

  if (ws_size >= needA) {
    // ================= Tier A: fully batched (~102 MB) =================
    u16* QK = (u16*)take((size_t)Bb * SD2 * 2);   // [B*S][2048] = Q|K
    u16* VT = (u16*)take((size_t)N_X * 2);        // [B][D][S]
    u16* E  = (u16*)take((size_t)Bb * SS * 2);    // bf16 exp(scores)

    // fused QK|VT: 1024 QK tiles + 512 VT tiles = 1536 blocks, one tail
    gemm_nt<5><<<dim3(1024 + 512), 256, 0, stream>>>(
        xn, WT3, QK, flag, nullptr, /*VT bn count*/64, D, D, D, /*ldc*/S,
        0, 0, /*sC*/SD, 0, 1.f, 0, /*nQK*/1024, VT);

    // E = exp(Q K^T * scl) bf16 + row-sums sigma (pure GEMM, 136x4 blocks)
    gemm_nt<3><<<dim3(NTRI, 1, Bb), 256, 0, stream>>>(
        QK, QK + 1024, E, flag, sigma, S, D, D2, D2, S,
        SD2, SD2, SS, 0, scl, 0, NTRI, nullptr);

    // PV split-K: rows<1024 direct; rows>=1024 two half-K partials into the
    // dead QK buffer (scores already consumed it), then combine.
    gemm_nt<6><<<dim3(D / BN, 24, Bb), 256, 0, stream>>>(
        E, VT, d_out, flag, sigma, S, S, S, S, D,
        SS, SD, SD, 0, 1.f, 0, 0, (u16*)QK);
    pv_combine<<<4096, 256, 0, stream>>>((const float*)QK, sigma, d_out, flag);
  } else {
    // ================= Tier C: per-batch (~42 MB) =================
    u16* QKb = (u16*)take((size_t)SD2 * 2);
    u16* VTb = (u16*)take((size_t)SD * 2);
    u16* Eb  = (u16*)take((size_t)SS * 2);

    for (int b = 0; b < Bb; ++b) {
      // fused QK|VT per batch: 256 QK tiles + 128 VT tiles
      gemm_nt<5><<<dim3(256 + 128), 256, 0, stream>>>(
          xn + (long)b * SD, WT3, QKb, flag, nullptr, /*VT bn*/16, D, D, D, S,
          0, 0, /*sC*/0, 0, 1.f, 0, /*nQK*/256, VTb);

      gemm_nt<3><<<dim3(NTRI, 1, 1), 256, 0, stream>>>(
          QKb, QKb + 1024, Eb, flag, sigma + (long)b * S, S, D, D2, D2, S,
          0, 0, 0, 0, scl, 0, NTRI, nullptr);

      gemm_nt<2><<<dim3(D / BN, S / BM, 1), 256, 0, stream>>>(
          Eb, VTb, d_out, flag, sigma + (long)b * S, S, S, S, S, D,
          0, 0, 0, (long)b * SD, 1.f, 1, 0, nullptr);
    }
  }
}

// Round 12
// 229.607 us; speedup vs baseline: 1.0456x; 1.0456x over previous
//
#include <hip/hip_runtime.h>
#include <stdint.h>

typedef unsigned short u16;
typedef unsigned int u32;
typedef __bf16 bf16x8 __attribute__((ext_vector_type(8)));
typedef float f32x4 __attribute__((ext_vector_type(4)));

#define BM 128
#define BN 128
#define BK 64

__device__ __forceinline__ u16 f2bf(float x) {
  union { float f; uint32_t u; } c; c.f = x;
  uint32_t r = (c.u + 0x7FFFu + ((c.u >> 16) & 1u)) >> 16;
  return (u16)r;
}
__device__ __forceinline__ float bf2f(u16 v) {
  union { uint32_t u; float f; } c; c.u = ((uint32_t)v) << 16;
  return c.f;
}

// async global->LDS, 16B per lane; LDS dest = wave-uniform base + lane*16
__device__ __forceinline__ void async_copy16(const u16* g, u16* l) {
  __builtin_amdgcn_global_load_lds(
      (const __attribute__((address_space(1))) void*)g,
      (__attribute__((address_space(3))) void*)l,
      16, 0, 0);
}

__global__ void zerofill_u16(u16* __restrict__ p) {
  long i = (long)blockIdx.x * 256 + threadIdx.x;
  p[i] = 0;
}

// ---------- fused prep: dtype self-detect + x normalize + W transnorm + ----
// sigma zero. Every block samples the SAME first 8192 u16 of Wq: bf16
// weights give 0 exp==0xFF hits; f32 mantissa halves give ~16 (P(0)~1e-7).
__global__ __launch_bounds__(256)
void prep(const void* __restrict__ xs, const void* __restrict__ w0,
          const void* __restrict__ w1, const void* __restrict__ w2,
          u16* __restrict__ xn, u16* __restrict__ WT3, u32* __restrict__ flag,
          float* __restrict__ sigma, int nxb)
{
  __shared__ int sh_hits;
  __shared__ u16 tile[64][72];
  if (threadIdx.x == 0) sh_hits = 0;
  __syncthreads();
  {
    const u16* w = (const u16*)w0;
    int h = 0;
    for (int i = threadIdx.x; i < 8192; i += 256)
      if ((w[i] & 0x7F80u) == 0x7F80u) h++;
    if (h) atomicAdd(&sh_hits, h);
  }
  __syncthreads();
  const bool isf32 = (sh_hits > 0);
  const int blk = blockIdx.x;
  const int tid = threadIdx.x;
  if (blk == 0 && tid == 0) *flag = isf32 ? 1000u : 0u;

  if (blk < nxb) {
    long i = ((long)blk * 256 + tid) * 8;
    u16 o[8];
    if (isf32) {
      const float* s = (const float*)xs + i;
      f32x4 a = *(const f32x4*)s;
      f32x4 b = *(const f32x4*)(s + 4);
#pragma unroll
      for (int c = 0; c < 4; ++c) { o[c] = f2bf(a[c]); o[c + 4] = f2bf(b[c]); }
    } else {
      *(uint4*)o = *(const uint4*)((const u16*)xs + i);
    }
    *(uint4*)(xn + i) = *(uint4*)o;
  } else if (blk < nxb + 768) {
    const int Dd = 1024;
    int t = blk - nxb;
    int z = t >> 8;
    int r = t & 255;
    const int r0 = (r >> 4) * 64, c0 = (r & 15) * 64;
    const void* src = (z == 0) ? w0 : (z == 1) ? w1 : w2;
    u16* out = WT3 + (long)z * Dd * Dd;
#pragma unroll
    for (int p = 0; p < 2; ++p) {
      int v = tid + p * 256;
      int row = v >> 3, c8 = (v & 7) * 8;
      u16 tt[8];
      if (isf32) {
        const float* sp = (const float*)src + (long)(r0 + row) * Dd + c0 + c8;
        f32x4 a = *(const f32x4*)sp;
        f32x4 b = *(const f32x4*)(sp + 4);
#pragma unroll
        for (int c = 0; c < 4; ++c) { tt[c] = f2bf(a[c]); tt[c + 4] = f2bf(b[c]); }
      } else {
        *(uint4*)tt = *(const uint4*)((const u16*)src + (long)(r0 + row) * Dd + c0 + c8);
      }
#pragma unroll
      for (int c = 0; c < 8; ++c) tile[row][c8 + c] = tt[c];
    }
    __syncthreads();
#pragma unroll
    for (int p = 0; p < 2; ++p) {
      int v = tid + p * 256;
      int oc = v >> 3, r8 = (v & 7) * 8;
      union { uint4 q; u16 s[8]; } tt;
#pragma unroll
      for (int c = 0; c < 8; ++c) tt.s[c] = tile[r8 + c][oc];
      *(uint4*)(out + (long)(c0 + oc) * Dd + r0 + r8) = tt.q;
    }
  } else {
    int t = blk - (nxb + 768);
    *(f32x4*)(sigma + ((long)t * 256 + tid) * 4) = f32x4{0.f, 0.f, 0.f, 0.f};
  }
}

// ---------- NT GEMM, 16x16x32 MFMA core (r5/r7-verified: 0 conflicts) ------
// LDS XOR-swizzled on the global-read side: slot [r][p] holds global chunk
// p^(r&7). 16-row fragment geometry => only 2-way bank aliasing (free).
// DO NOT switch to 32x32 fragments: 4-way structural conflict (r6).
// DO NOT replace with 1-blk/CU pipelined variants: r1/r2/r3 all regressed.
// DO NOT shrink BM to 64 to add blocks: r7 regressed PV 44->52 us — staging
// bytes per MFMA rise 50%; occupancy gain did not pay for it.
// DO NOT split-K the long PV blocks: r10 regressed total +3 us — the +80 MB
// partial/combine traffic exceeds the ~10 us critical-path saving.
// r9: QK|VT fusion (MODE 5) = -10 us. Fused dispatch runs at ~851 TF, the
// m97-structure ceiling — do not re-attack.
// __launch_bounds__(256,4): 32KB LDS x4 = 128KB <= 160KB; 64 arch + 64 acc
// VGPR = 128 unified -> 4 waves/SIMD.
// MODE 2: PV — flag-selected bf16/f32 out, divided by sigma[row]; trik=1
//         (longest blocks dispatched first pairs long+short per CU).
// MODE 3: scores — supertile-ordered triangular grid (136 tiles/batch).
//         bf16 exp(acc*scale), causal mask on diagonal, atomic row-sums.
// MODE 5: fused QK|VT: t<ntri QK tile; t>=ntri VT tile (operands swapped,
//         col->batch write). sigStride carries VT bn count.
template <int MODE>
__global__ __launch_bounds__(256, 4)
void gemm_nt(const u16* __restrict__ A, const u16* __restrict__ B, void* __restrict__ Cv,
             const u32* __restrict__ flag, float* __restrict__ sigma, int sigStride,
             int K, int lda, int ldb, int ldc,
             long sA, long sB, long sC, long cOff,
             float scale, int trik, int ntri, u16* __restrict__ vtOut)
{
  __shared__ u16 As[BM * BK];
  __shared__ u16 Bs[BN * BK];
  const int bz = blockIdx.z;
  const int tid = threadIdx.x;

  int bm, bn;
  bool isVT = false;
  if constexpr (MODE == 3) {
    // supertile-ordered triangle decode (16x16 tiles, 4x4 supertiles)
    const int t = blockIdx.x;
    const int cum[11] = {0, 10, 26, 36, 52, 68, 78, 94, 110, 126, 136};
    const int ssm[10] = {0, 1, 1, 2, 2, 2, 3, 3, 3, 3};
    const int ssn[10] = {0, 0, 1, 0, 1, 2, 0, 1, 2, 3};
    int s = 0;
    while (cum[s + 1] <= t) ++s;
    const int l = t - cum[s];
    const int sm = ssm[s], sn = ssn[s];
    int tm, tn;
    if (sm == sn) {                 // diagonal supertile: triangular 10
      tm = 0;
      while ((tm + 1) * (tm + 2) / 2 <= l) ++tm;
      tn = l - tm * (tm + 1) / 2;
    } else { tm = l >> 2; tn = l & 3; }
    bm = sm * 4 + tm;
    bn = sn * 4 + tn;
    (void)ntri;
  } else if constexpr (MODE == 5) {
    const int t = blockIdx.x;
    if (t < ntri) {                 // QK half: bn fastest (16 wide)
      bm = t >> 4; bn = t & 15;
    } else {                        // VT half: bn fastest (sigStride wide)
      isVT = true;
      const int t2 = t - ntri;
      bm = t2 / sigStride; bn = t2 % sigStride;
      const u16* tmp = A;
      A = B + (long)2048 * 1024;    // WvT base inside WT3
      B = tmp;                      // xn becomes the B operand
    }
  } else {
    bm = blockIdx.y;
    if (trik) bm = gridDim.y - 1 - bm;         // longest blocks first
    bn = blockIdx.x;
  }

  A += (long)bz * sA;
  B += (long)bz * sB;

  const int wid  = tid >> 6;
  const int lane = tid & 63;
  const int l16  = lane & 15;
  const int lk   = lane >> 4;                   // 0..3
  const int srow = lane >> 3;                   // 0..7 (staging row in slab)
  const int swz  = ((lane & 7) ^ srow) * 8;     // swizzled staging col
  const int m0 = bm * BM, n0 = bn * BN;

  int nk = K / BK;
  if (trik) { int lim = (m0 + BM) / BK; if (lim < nk) nk = lim; }

  f32x4 acc[4][4] = {};

  for (int kt = 0; kt < nk; ++kt) {
    const int k0 = kt * BK;
#pragma unroll
    for (int c = 0; c < 4; ++c) {
      const int rb = wid * 32 + c * 8;          // wave-uniform 8-row slab base
      async_copy16(A + (long)(m0 + rb + srow) * lda + (k0 + swz), As + rb * BK);
      async_copy16(B + (long)(n0 + rb + srow) * ldb + (k0 + swz), Bs + rb * BK);
    }
    __syncthreads();
#pragma unroll
    for (int kh = 0; kh < 2; ++kh) {
      bf16x8 av[4], bv[4];
#pragma unroll
      for (int i = 0; i < 4; ++i) {
        const int Ra = (wid >> 1) * 64 + i * 16 + l16;
        const int Rb = (wid & 1)  * 64 + i * 16 + l16;
        const int ca = ((kh * 4 + lk) ^ (l16 & 7)) * 8;  // de-swizzled chunk
        av[i] = *(const bf16x8*)(As + Ra * BK + ca);
        bv[i] = *(const bf16x8*)(Bs + Rb * BK + ca);
      }
#pragma unroll
      for (int mi = 0; mi < 4; ++mi)
#pragma unroll
        for (int ni = 0; ni < 4; ++ni)
          acc[mi][ni] = __builtin_amdgcn_mfma_f32_16x16x32_bf16(av[mi], bv[ni], acc[mi][ni], 0, 0, 0);
    }
    __syncthreads();
  }

  // C/D layout (m89-verified): col = lane&15, row = (lane>>4)*4 + reg
  const int rb0 = m0 + (wid >> 1) * 64;
  const int cb0 = n0 + (wid & 1) * 64;
  const long cbase = (long)bz * sC + cOff;

  if constexpr (MODE == 3) {
    // exp + causal mask + bf16 store + atomic row-sums (of the SAME
    // bf16-rounded values PV will consume, so weight errors cancel)
    u16* Cp = (u16*)Cv;
    const bool diag = (bm == bn);
    float* sig = sigma + (long)bz * sigStride;
#pragma unroll
    for (int mi = 0; mi < 4; ++mi)
#pragma unroll
      for (int r = 0; r < 4; ++r) {
        const int row = rb0 + mi * 16 + lk * 4 + r;
        float part = 0.f;
#pragma unroll
        for (int ni = 0; ni < 4; ++ni) {
          const int col = cb0 + ni * 16 + l16;
          float ev = __expf(acc[mi][ni][r] * scale);
          if (diag && col > row) ev = 0.f;
          u16 b = f2bf(ev);
          part += bf2f(b);
          Cp[cbase + (long)row * ldc + col] = b;
        }
#pragma unroll
        for (int o = 1; o < 16; o <<= 1) part += __shfl_xor(part, o);
        if (l16 == 0) atomicAdd(&sig[row], part);
      }
  } else if constexpr (MODE == 5) {
    if (isVT) {
      // VT writeout: row=d, col=global s; batch from col>>11
#pragma unroll
      for (int mi = 0; mi < 4; ++mi)
#pragma unroll
        for (int r = 0; r < 4; ++r) {
          const int row = rb0 + mi * 16 + lk * 4 + r;
#pragma unroll
          for (int ni = 0; ni < 4; ++ni) {
            const int col = cb0 + ni * 16 + l16;
            const long idx = (long)row * ldc + (long)(col >> 11) * sC + (col & 2047);
            vtOut[idx] = f2bf(acc[mi][ni][r]);
          }
        }
    } else {
      // QK writeout (bf16, row-major ldc=2048)
      u16* Cp = (u16*)Cv;
#pragma unroll
      for (int mi = 0; mi < 4; ++mi)
#pragma unroll
        for (int r = 0; r < 4; ++r) {
          const int row = rb0 + mi * 16 + lk * 4 + r;
#pragma unroll
          for (int ni = 0; ni < 4; ++ni) {
            const int col = cb0 + ni * 16 + l16;
            Cp[(long)row * 2048 + col] = f2bf(acc[mi][ni][r]);
          }
        }
    }
  } else {
    const bool f32out = (MODE == 2) && (*flag > 32);
    const float* sig = (MODE == 2) ? (sigma + (long)bz * sigStride) : nullptr;
#pragma unroll
    for (int mi = 0; mi < 4; ++mi)
#pragma unroll
      for (int r = 0; r < 4; ++r) {
        const int row = rb0 + mi * 16 + lk * 4 + r;
        float rs = scale;
        if constexpr (MODE == 2) rs = 1.0f / sig[row];
#pragma unroll
        for (int ni = 0; ni < 4; ++ni) {
          const int col = cb0 + ni * 16 + l16;
          const float v = acc[mi][ni][r] * rs;
          const long idx = cbase + (long)row * ldc + col;
          if (f32out) ((float*)Cv)[idx] = v;
          else        ((u16*)Cv)[idx]   = f2bf(v);
        }
      }
  }
}

extern "C" void kernel_launch(void* const* d_in, const int* in_sizes, int n_in,
                              void* d_out, int out_size, void* d_ws, size_t ws_size,
                              hipStream_t stream)
{
  (void)in_sizes; (void)n_in; (void)out_size;
  const int Bb = 4, S = 2048, D = 1024, D2 = 2048;
  const long SD  = (long)S * D;           // 2,097,152
  const long SD2 = (long)S * D2;          // 4,194,304 (QK per-batch stride)
  const long SS  = (long)S * S;           // 4,194,304
  const long N_X = (long)Bb * SD;         // 8,388,608
  const long N_W = (long)D * D;           // 1,048,576
  const int NTRI = 16 * 17 / 2;           // 136 lower-triangle tiles

  char* ws = (char*)d_ws;
  size_t off = 0;
  auto take = [&](size_t bytes) -> void* {
    void* p = ws + off;
    off = (off + bytes + 255) & ~((size_t)255);
    return p;
  };

  // ---- common allocations (~22 MB)
  u32*   flag  = (u32*)take(4096);
  float* sigma = (float*)take((size_t)Bb * S * 4);  // 32 KB row-sums
  u16*   xn    = (u16*)take((size_t)N_X * 2);
  u16*   WT3   = (u16*)take((size_t)3 * N_W * 2);
  const size_t off_common = off;

  const size_t needA = off_common + (size_t)(Bb * SD2 * 2)     // QK 32 MB
                     + (size_t)(N_X * 2)                       // VT 16 MB
                     + (size_t)(Bb * SS * 2) + 4096;           // E bf16 32 MB
  const size_t needC = off_common + (size_t)(SD2 * 2)          // QKb 8 MB
                     + (size_t)(SD * 2)                        // VTb 4 MB
                     + (size_t)(SS * 2) + 4096;                // Eb 8 MB

  if (ws_size < needC) {
    zerofill_u16<<<(int)(N_X / 256), 256, 0, stream>>>((u16*)d_out);
    return;
  }

  // ---- fused prep: detect + normalize x + transnorm W + zero sigma ----
  const int nxb = (int)(N_X / 2048);   // 4096 x-blocks
  prep<<<nxb + 768 + 8, 256, 0, stream>>>(d_in[0], d_in[1], d_in[2], d_in[3],
                                          xn, WT3, flag, sigma, nxb);

  const float scl = 0.03125f;  // 1024^-0.5

  if (ws_size >= needA) {
    // ================= Tier A: fully batched (~102 MB) =================
    u16* QK = (u16*)take((size_t)Bb * SD2 * 2);   // [B*S][2048] = Q|K
    u16* VT = (u16*)take((size_t)N_X * 2);        // [B][D][S]
    u16* E  = (u16*)take((size_t)Bb * SS * 2);    // bf16 exp(scores)

    // fused QK|VT: 1024 QK tiles + 512 VT tiles = 1536 blocks, one tail
    gemm_nt<5><<<dim3(1024 + 512), 256, 0, stream>>>(
        xn, WT3, QK, flag, nullptr, /*VT bn count*/64, D, D, D, /*ldc*/S,
        0, 0, /*sC*/SD, 0, 1.f, 0, /*nQK*/1024, VT);

    // E = exp(Q K^T * scl) bf16 + row-sums sigma (pure GEMM, 136x4 blocks)
    gemm_nt<3><<<dim3(NTRI, 1, Bb), 256, 0, stream>>>(
        QK, QK + 1024, E, flag, sigma, S, D, D2, D2, S,
        SD2, SD2, SS, 0, scl, 0, NTRI, nullptr);

    // out = (E V) / sigma, causal K pruning, dtype-adaptive writeout
    gemm_nt<2><<<dim3(D / BN, S / BM, Bb), 256, 0, stream>>>(
        E, VT, d_out, flag, sigma, S, S, S, S, D,
        SS, SD, SD, 0, 1.f, 1, 0, nullptr);
  } else {
    // ================= Tier C: per-batch (~42 MB) =================
    u16* QKb = (u16*)take((size_t)SD2 * 2);
    u16* VTb = (u16*)take((size_t)SD * 2);
    u16* Eb  = (u16*)take((size_t)SS * 2);

    for (int b = 0; b < Bb; ++b) {
      // fused QK|VT per batch: 256 QK tiles + 128 VT tiles
      gemm_nt<5><<<dim3(256 + 128), 256, 0, stream>>>(
          xn + (long)b * SD, WT3, QKb, flag, nullptr, /*VT bn*/16, D, D, D, S,
          0, 0, /*sC*/0, 0, 1.f, 0, /*nQK*/256, VTb);

      gemm_nt<3><<<dim3(NTRI, 1, 1), 256, 0, stream>>>(
          QKb, QKb + 1024, Eb, flag, sigma + (long)b * S, S, D, D2, D2, S,
          0, 0, 0, 0, scl, 0, NTRI, nullptr);

      gemm_nt<2><<<dim3(D / BN, S / BM, 1), 256, 0, stream>>>(
          Eb, VTb, d_out, flag, sigma + (long)b * S, S, S, S, S, D,
          0, 0, 0, (long)b * SD, 1.f, 1, 0, nullptr);
    }
  }
}